// Round 4
// baseline (238.946 us; speedup 1.0000x reference)
//
#include <hip/hip_runtime.h>
#include <math.h>

// Problem constants (B,S,E) = (8, 4096, 1024), all fp32.
constexpr int Bc  = 8;
constexpr int Sc  = 4096;
constexpr int Ec  = 1024;
constexpr int BEc = Bc * Ec;   // 8192 (b,e) columns
constexpr int NP  = 8;         // second-stage reduction parts
constexpr int NSmain = 256;    // s-chunks for the streaming kernels
constexpr int SCmain = Sc / NSmain;  // 16 rows per chunk

// native 4-wide float vector (works with nontemporal builtins)
typedef float f4 __attribute__((ext_vector_type(4)));

// fast feature map: gelu(x)+1 with A&S 7.1.26 erf (|eps| <= 1.5e-7)
__device__ __forceinline__ float fast_feat(float x) {
    float a = fabsf(x) * 0.70710678118654752f;          // |x|/sqrt(2)
    float t = __builtin_amdgcn_rcpf(fmaf(0.3275911f, a, 1.0f));
    float p = fmaf(1.061405429f, t, -1.453152027f);
    p = fmaf(p, t, 1.421413741f);
    p = fmaf(p, t, -0.284496736f);
    p = fmaf(p, t, 0.254829592f);
    float e  = __expf(-a * a);
    float er = fmaf(-p * t, e, 1.0f);                   // erf(|x|/sqrt2)
    er = copysignf(er, x);
    return fmaf(0.5f * x, 1.0f + er, 1.0f);
}
__device__ __forceinline__ f4 feat4(f4 v) {
    f4 r;
    r.x = fast_feat(v.x); r.y = fast_feat(v.y);
    r.z = fast_feat(v.z); r.w = fast_feat(v.w);
    return r;
}

// ---------------- K1: colsum(qf*kf), max(qf), min(qf) per (b,e), s-chunk ----
// depth-2 register prefetch pipeline, full unroll (SC compile-time).
template<int SC>
__global__ void __launch_bounds__(256, 8)
sa_stats_part(const float* __restrict__ qp, const float* __restrict__ kp,
              float* __restrict__ psum, float* __restrict__ pmax,
              float* __restrict__ pmin) {
    const int chunk = blockIdx.x, b = blockIdx.y;
    const int e = threadIdx.x * 4;
    const float* qb = qp + (b * Sc + chunk * SC) * Ec + e;
    const float* kb = kp + (b * Sc + chunk * SC) * Ec + e;

    f4 qr[2], kr[2];
    qr[0] = *(const f4*)(qb);
    kr[0] = __builtin_nontemporal_load((const f4*)(kb));
    qr[1] = *(const f4*)(qb + Ec);
    kr[1] = __builtin_nontemporal_load((const f4*)(kb + Ec));

    f4 s  = (f4)(0.f);
    f4 mx = (f4)(-1e30f);
    f4 mn = (f4)( 1e30f);
#pragma unroll
    for (int r = 0; r < SC; ++r) {
        f4 qv = qr[r & 1], kv = kr[r & 1];
        if (r + 2 < SC) {   // prefetch row r+2 (static after unroll)
            qr[r & 1] = *(const f4*)(qb + (r + 2) * Ec);
            kr[r & 1] = __builtin_nontemporal_load((const f4*)(kb + (r + 2) * Ec));
        }
        f4 qf = feat4(qv);
        f4 kf = feat4(kv);
        s.x = fmaf(qf.x, kf.x, s.x);  mx.x = fmaxf(mx.x, qf.x);  mn.x = fminf(mn.x, qf.x);
        s.y = fmaf(qf.y, kf.y, s.y);  mx.y = fmaxf(mx.y, qf.y);  mn.y = fminf(mn.y, qf.y);
        s.z = fmaf(qf.z, kf.z, s.z);  mx.z = fmaxf(mx.z, qf.z);  mn.z = fminf(mn.z, qf.z);
        s.w = fmaf(qf.w, kf.w, s.w);  mx.w = fmaxf(mx.w, qf.w);  mn.w = fminf(mn.w, qf.w);
    }
    const int o = chunk * BEc + b * Ec + e;
    *(f4*)(psum + o) = s;
    *(f4*)(pmax + o) = mx;
    *(f4*)(pmin + o) = mn;
}

// K2a: reduce NS stats chunks -> NP parts. grid = (NP, BEc/256).
__global__ void __launch_bounds__(256)
sa_red3(const float* __restrict__ psum, const float* __restrict__ pmax,
        const float* __restrict__ pmin, float* __restrict__ psumB,
        float* __restrict__ pmaxB, float* __restrict__ pminB, int SC2) {
    const int id = blockIdx.y * 256 + threadIdx.x;
    const int p  = blockIdx.x;
    float s = 0.f, mx = -1e30f, mn = 1e30f;
    int off = p * SC2 * BEc + id;
    for (int ch = 0; ch < SC2; ++ch, off += BEc) {
        s += psum[off];
        mx = fmaxf(mx, pmax[off]);
        mn = fminf(mn, pmin[off]);
    }
    psumB[p * BEc + id] = s;
    pmaxB[p * BEc + id] = mx;
    pminB[p * BEc + id] = mn;
}

// K2b: finalize stats -> c[b,e] = colsum/32; eMax = c>=0 ? c*max : c*min
__global__ void __launch_bounds__(256)
sa_stats_fin(const float* __restrict__ psumB, const float* __restrict__ pmaxB,
             const float* __restrict__ pminB, float* __restrict__ cbuf,
             float* __restrict__ embuf) {
    const int id = blockIdx.x * blockDim.x + threadIdx.x;
    float s = 0.f, mx = -1e30f, mn = 1e30f;
#pragma unroll
    for (int p = 0; p < NP; ++p) {
        s += psumB[p * BEc + id];
        mx = fmaxf(mx, pmaxB[p * BEc + id]);
        mn = fminf(mn, pminB[p * BEc + id]);
    }
    const float c = s * (1.0f / 32.0f);   // 1/sqrt(1024)
    cbuf[id]  = c;
    embuf[id] = (c >= 0.f) ? c * mx : c * mn;
}

// ---------------- K3: partial denominator sum_s exp(c*qf - eMax) ------------
template<int SC>
__global__ void __launch_bounds__(256, 8)
sa_den_part(const float* __restrict__ qp, const float* __restrict__ cbuf,
            const float* __restrict__ embuf, float* __restrict__ pden) {
    const int chunk = blockIdx.x, b = blockIdx.y;
    const int e = threadIdx.x * 4;
    const f4 c4 = *(const f4*)(cbuf + b * Ec + e);
    const f4 m4 = *(const f4*)(embuf + b * Ec + e);
    const float* qb = qp + (b * Sc + chunk * SC) * Ec + e;

    f4 qr[2];
    qr[0] = *(const f4*)(qb);
    qr[1] = *(const f4*)(qb + Ec);

    f4 d = (f4)(0.f);
#pragma unroll
    for (int r = 0; r < SC; ++r) {
        f4 qv = qr[r & 1];
        if (r + 2 < SC) qr[r & 1] = *(const f4*)(qb + (r + 2) * Ec);
        f4 qf = feat4(qv);
        d.x += __expf(fmaf(c4.x, qf.x, -m4.x));
        d.y += __expf(fmaf(c4.y, qf.y, -m4.y));
        d.z += __expf(fmaf(c4.z, qf.z, -m4.z));
        d.w += __expf(fmaf(c4.w, qf.w, -m4.w));
    }
    const int o = chunk * BEc + b * Ec + e;
    *(f4*)(pden + o) = d;
}

// K4a: reduce NS denom chunks -> NP parts. grid = (NP, BEc/256).
__global__ void __launch_bounds__(256)
sa_red1(const float* __restrict__ pden, float* __restrict__ pdenB, int SC2) {
    const int id = blockIdx.y * 256 + threadIdx.x;
    const int p  = blockIdx.x;
    float s = 0.f;
    int off = p * SC2 * BEc + id;
    for (int ch = 0; ch < SC2; ++ch, off += BEc) s += pden[off];
    pdenB[p * BEc + id] = s;
}

// K4b: finalize denominator -> reciprocal
__global__ void __launch_bounds__(256)
sa_den_fin(const float* __restrict__ pdenB, float* __restrict__ rdbuf) {
    const int id = blockIdx.x * blockDim.x + threadIdx.x;
    float s = 0.f;
#pragma unroll
    for (int p = 0; p < NP; ++p) s += pdenB[p * BEc + id];
    rdbuf[id] = 1.0f / s;
}

// ---------------- K5: out = exp(c*qf - eMax) * rdenom * values --------------
template<int SC>
__global__ void __launch_bounds__(256, 8)
sa_out(const float* __restrict__ qp, const float* __restrict__ vp,
       const float* __restrict__ cbuf, const float* __restrict__ embuf,
       const float* __restrict__ rdbuf, float* __restrict__ outp) {
    const int chunk = blockIdx.x, b = blockIdx.y;
    const int e = threadIdx.x * 4;
    const f4 c4 = *(const f4*)(cbuf + b * Ec + e);
    const f4 m4 = *(const f4*)(embuf + b * Ec + e);
    const f4 r4 = *(const f4*)(rdbuf + b * Ec + e);
    const int base0 = (b * Sc + chunk * SC) * Ec + e;
    const float* qb = qp + base0;
    const float* vb = vp + base0;
    float* ob = outp + base0;

    f4 qr[2], vr[2];
    qr[0] = *(const f4*)(qb);
    vr[0] = __builtin_nontemporal_load((const f4*)(vb));
    qr[1] = *(const f4*)(qb + Ec);
    vr[1] = __builtin_nontemporal_load((const f4*)(vb + Ec));

#pragma unroll
    for (int r = 0; r < SC; ++r) {
        f4 qv = qr[r & 1], vv = vr[r & 1];
        if (r + 2 < SC) {
            qr[r & 1] = *(const f4*)(qb + (r + 2) * Ec);
            vr[r & 1] = __builtin_nontemporal_load((const f4*)(vb + (r + 2) * Ec));
        }
        f4 qf = feat4(qv);
        f4 o;
        o.x = __expf(fmaf(c4.x, qf.x, -m4.x)) * r4.x * vv.x;
        o.y = __expf(fmaf(c4.y, qf.y, -m4.y)) * r4.y * vv.y;
        o.z = __expf(fmaf(c4.z, qf.z, -m4.z)) * r4.z * vv.z;
        o.w = __expf(fmaf(c4.w, qf.w, -m4.w)) * r4.w * vv.w;
        __builtin_nontemporal_store(o, (f4*)(ob + r * Ec));
    }
}

extern "C" void kernel_launch(void* const* d_in, const int* in_sizes, int n_in,
                              void* d_out, int out_size, void* d_ws, size_t ws_size,
                              hipStream_t stream) {
    const float* q = (const float*)d_in[0];
    const float* k = (const float*)d_in[1];
    const float* v = (const float*)d_in[2];
    float* out = (float*)d_out;

    const int NS = NSmain;     // ws usage ~25.5 MB (R3 confirmed it fits)
    const int SC2 = NS / NP;

    float* w     = (float*)d_ws;
    float* psum  = w;
    float* pmax  = psum  + (size_t)NS * BEc;
    float* pmin  = pmax  + (size_t)NS * BEc;
    float* psumB = pmin  + (size_t)NS * BEc;
    float* pmaxB = psumB + (size_t)NP * BEc;
    float* pminB = pmaxB + (size_t)NP * BEc;
    float* cbuf  = pminB + (size_t)NP * BEc;
    float* embuf = cbuf  + BEc;
    float* rdbuf = embuf + BEc;
    float* pden  = psum;    // reused after K2a
    float* pdenB = psumB;   // reused after K2b

    dim3 gridP(NS, Bc);
    dim3 gridR(NP, BEc / 256);
    sa_stats_part<SCmain><<<gridP, 256, 0, stream>>>(q, k, psum, pmax, pmin);
    sa_red3<<<gridR, 256, 0, stream>>>(psum, pmax, pmin, psumB, pmaxB, pminB, SC2);
    sa_stats_fin<<<BEc / 256, 256, 0, stream>>>(psumB, pmaxB, pminB, cbuf, embuf);
    sa_den_part<SCmain><<<gridP, 256, 0, stream>>>(q, cbuf, embuf, pden);
    sa_red1<<<gridR, 256, 0, stream>>>(pden, pdenB, SC2);
    sa_den_fin<<<BEc / 256, 256, 0, stream>>>(pdenB, rdbuf);
    sa_out<SCmain><<<gridP, 256, 0, stream>>>(q, v, cbuf, embuf, rdbuf, out);
}

// Round 5
// 157.057 us; speedup vs baseline: 1.5214x; 1.5214x over previous
//
#include <hip/hip_runtime.h>
#include <math.h>

// Problem constants (B,S,E) = (8, 4096, 1024), all fp32.
constexpr int Bc  = 8;
constexpr int Sc  = 4096;
constexpr int Ec  = 1024;
constexpr int BEc = Bc * Ec;   // 8192 (b,e) columns
constexpr int NP  = 8;         // second-stage reduction parts
constexpr int NSmain = 256;    // s-chunks for the streaming kernels
constexpr int SCmain = Sc / NSmain;  // 16 rows per chunk

// native 4-wide float vector (works with nontemporal builtins)
typedef float f4 __attribute__((ext_vector_type(4)));

// fast feature map: gelu(x)+1 with A&S 7.1.26 erf (|eps| <= 1.5e-7)
__device__ __forceinline__ float fast_feat(float x) {
    float a = fabsf(x) * 0.70710678118654752f;          // |x|/sqrt(2)
    float t = __builtin_amdgcn_rcpf(fmaf(0.3275911f, a, 1.0f));
    float p = fmaf(1.061405429f, t, -1.453152027f);
    p = fmaf(p, t, 1.421413741f);
    p = fmaf(p, t, -0.284496736f);
    p = fmaf(p, t, 0.254829592f);
    float e  = __expf(-a * a);
    float er = fmaf(-p * t, e, 1.0f);                   // erf(|x|/sqrt2)
    er = copysignf(er, x);
    return fmaf(0.5f * x, 1.0f + er, 1.0f);
}
__device__ __forceinline__ f4 feat4(f4 v) {
    f4 r;
    r.x = fast_feat(v.x); r.y = fast_feat(v.y);
    r.z = fast_feat(v.z); r.w = fast_feat(v.w);
    return r;
}

// ---------------- K1: colsum(qf*kf), max(qf), min(qf) per (b,e), s-chunk ----
// depth-3 register prefetch pipeline, full unroll (SC compile-time).
// NOTE: no min-wave clamp — R4's (256,8) forced VGPR=32 and spilled 50 MB.
template<int SC>
__global__ void __launch_bounds__(256)
sa_stats_part(const float* __restrict__ qp, const float* __restrict__ kp,
              float* __restrict__ psum, float* __restrict__ pmax,
              float* __restrict__ pmin) {
    constexpr int D = 3;       // prefetch depth
    const int chunk = blockIdx.x, b = blockIdx.y;
    const int e = threadIdx.x * 4;
    const float* qb = qp + (b * Sc + chunk * SC) * Ec + e;
    const float* kb = kp + (b * Sc + chunk * SC) * Ec + e;

    f4 qr[D], kr[D];
#pragma unroll
    for (int i = 0; i < D; ++i) {
        qr[i] = *(const f4*)(qb + i * Ec);
        kr[i] = __builtin_nontemporal_load((const f4*)(kb + i * Ec));
    }

    f4 s  = (f4)(0.f);
    f4 mx = (f4)(-1e30f);
    f4 mn = (f4)( 1e30f);
#pragma unroll
    for (int r = 0; r < SC; ++r) {
        f4 qv = qr[r % D], kv = kr[r % D];
        if (r + D < SC) {   // prefetch row r+D (static after unroll)
            qr[r % D] = *(const f4*)(qb + (r + D) * Ec);
            kr[r % D] = __builtin_nontemporal_load((const f4*)(kb + (r + D) * Ec));
        }
        f4 qf = feat4(qv);
        f4 kf = feat4(kv);
        s.x = fmaf(qf.x, kf.x, s.x);  mx.x = fmaxf(mx.x, qf.x);  mn.x = fminf(mn.x, qf.x);
        s.y = fmaf(qf.y, kf.y, s.y);  mx.y = fmaxf(mx.y, qf.y);  mn.y = fminf(mn.y, qf.y);
        s.z = fmaf(qf.z, kf.z, s.z);  mx.z = fmaxf(mx.z, qf.z);  mn.z = fminf(mn.z, qf.z);
        s.w = fmaf(qf.w, kf.w, s.w);  mx.w = fmaxf(mx.w, qf.w);  mn.w = fminf(mn.w, qf.w);
    }
    const int o = chunk * BEc + b * Ec + e;
    *(f4*)(psum + o) = s;
    *(f4*)(pmax + o) = mx;
    *(f4*)(pmin + o) = mn;
}

// K2a: reduce NS stats chunks -> NP parts. grid = (NP, BEc/256).
__global__ void __launch_bounds__(256)
sa_red3(const float* __restrict__ psum, const float* __restrict__ pmax,
        const float* __restrict__ pmin, float* __restrict__ psumB,
        float* __restrict__ pmaxB, float* __restrict__ pminB, int SC2) {
    const int id = blockIdx.y * 256 + threadIdx.x;
    const int p  = blockIdx.x;
    float s = 0.f, mx = -1e30f, mn = 1e30f;
    int off = p * SC2 * BEc + id;
    for (int ch = 0; ch < SC2; ++ch, off += BEc) {
        s += psum[off];
        mx = fmaxf(mx, pmax[off]);
        mn = fminf(mn, pmin[off]);
    }
    psumB[p * BEc + id] = s;
    pmaxB[p * BEc + id] = mx;
    pminB[p * BEc + id] = mn;
}

// K2b: finalize stats -> c[b,e] = colsum/32; eMax = c>=0 ? c*max : c*min
__global__ void __launch_bounds__(256)
sa_stats_fin(const float* __restrict__ psumB, const float* __restrict__ pmaxB,
             const float* __restrict__ pminB, float* __restrict__ cbuf,
             float* __restrict__ embuf) {
    const int id = blockIdx.x * blockDim.x + threadIdx.x;
    float s = 0.f, mx = -1e30f, mn = 1e30f;
#pragma unroll
    for (int p = 0; p < NP; ++p) {
        s += psumB[p * BEc + id];
        mx = fmaxf(mx, pmaxB[p * BEc + id]);
        mn = fminf(mn, pminB[p * BEc + id]);
    }
    const float c = s * (1.0f / 32.0f);   // 1/sqrt(1024)
    cbuf[id]  = c;
    embuf[id] = (c >= 0.f) ? c * mx : c * mn;
}

// ---------------- K3: partial denominator sum_s exp(c*qf - eMax) ------------
template<int SC>
__global__ void __launch_bounds__(256)
sa_den_part(const float* __restrict__ qp, const float* __restrict__ cbuf,
            const float* __restrict__ embuf, float* __restrict__ pden) {
    constexpr int D = 4;       // single stream -> deeper prefetch
    const int chunk = blockIdx.x, b = blockIdx.y;
    const int e = threadIdx.x * 4;
    const f4 c4 = *(const f4*)(cbuf + b * Ec + e);
    const f4 m4 = *(const f4*)(embuf + b * Ec + e);
    const float* qb = qp + (b * Sc + chunk * SC) * Ec + e;

    f4 qr[D];
#pragma unroll
    for (int i = 0; i < D; ++i) qr[i] = *(const f4*)(qb + i * Ec);

    f4 d = (f4)(0.f);
#pragma unroll
    for (int r = 0; r < SC; ++r) {
        f4 qv = qr[r % D];
        if (r + D < SC) qr[r % D] = *(const f4*)(qb + (r + D) * Ec);
        f4 qf = feat4(qv);
        d.x += __expf(fmaf(c4.x, qf.x, -m4.x));
        d.y += __expf(fmaf(c4.y, qf.y, -m4.y));
        d.z += __expf(fmaf(c4.z, qf.z, -m4.z));
        d.w += __expf(fmaf(c4.w, qf.w, -m4.w));
    }
    const int o = chunk * BEc + b * Ec + e;
    *(f4*)(pden + o) = d;
}

// K4a: reduce NS denom chunks -> NP parts. grid = (NP, BEc/256).
__global__ void __launch_bounds__(256)
sa_red1(const float* __restrict__ pden, float* __restrict__ pdenB, int SC2) {
    const int id = blockIdx.y * 256 + threadIdx.x;
    const int p  = blockIdx.x;
    float s = 0.f;
    int off = p * SC2 * BEc + id;
    for (int ch = 0; ch < SC2; ++ch, off += BEc) s += pden[off];
    pdenB[p * BEc + id] = s;
}

// K4b: finalize denominator -> reciprocal
__global__ void __launch_bounds__(256)
sa_den_fin(const float* __restrict__ pdenB, float* __restrict__ rdbuf) {
    const int id = blockIdx.x * blockDim.x + threadIdx.x;
    float s = 0.f;
#pragma unroll
    for (int p = 0; p < NP; ++p) s += pdenB[p * BEc + id];
    rdbuf[id] = 1.0f / s;
}

// ---------------- K5: out = exp(c*qf - eMax) * rdenom * values --------------
template<int SC>
__global__ void __launch_bounds__(256)
sa_out(const float* __restrict__ qp, const float* __restrict__ vp,
       const float* __restrict__ cbuf, const float* __restrict__ embuf,
       const float* __restrict__ rdbuf, float* __restrict__ outp) {
    constexpr int D = 3;
    const int chunk = blockIdx.x, b = blockIdx.y;
    const int e = threadIdx.x * 4;
    const f4 c4 = *(const f4*)(cbuf + b * Ec + e);
    const f4 m4 = *(const f4*)(embuf + b * Ec + e);
    const f4 r4 = *(const f4*)(rdbuf + b * Ec + e);
    const int base0 = (b * Sc + chunk * SC) * Ec + e;
    const float* qb = qp + base0;
    const float* vb = vp + base0;
    float* ob = outp + base0;

    f4 qr[D], vr[D];
#pragma unroll
    for (int i = 0; i < D; ++i) {
        qr[i] = *(const f4*)(qb + i * Ec);
        vr[i] = __builtin_nontemporal_load((const f4*)(vb + i * Ec));
    }

#pragma unroll
    for (int r = 0; r < SC; ++r) {
        f4 qv = qr[r % D], vv = vr[r % D];
        if (r + D < SC) {
            qr[r % D] = *(const f4*)(qb + (r + D) * Ec);
            vr[r % D] = __builtin_nontemporal_load((const f4*)(vb + (r + D) * Ec));
        }
        f4 qf = feat4(qv);
        f4 o;
        o.x = __expf(fmaf(c4.x, qf.x, -m4.x)) * r4.x * vv.x;
        o.y = __expf(fmaf(c4.y, qf.y, -m4.y)) * r4.y * vv.y;
        o.z = __expf(fmaf(c4.z, qf.z, -m4.z)) * r4.z * vv.z;
        o.w = __expf(fmaf(c4.w, qf.w, -m4.w)) * r4.w * vv.w;
        __builtin_nontemporal_store(o, (f4*)(ob + r * Ec));
    }
}

extern "C" void kernel_launch(void* const* d_in, const int* in_sizes, int n_in,
                              void* d_out, int out_size, void* d_ws, size_t ws_size,
                              hipStream_t stream) {
    const float* q = (const float*)d_in[0];
    const float* k = (const float*)d_in[1];
    const float* v = (const float*)d_in[2];
    float* out = (float*)d_out;

    const int NS = NSmain;     // ws usage ~25.5 MB (confirmed fits)
    const int SC2 = NS / NP;

    float* w     = (float*)d_ws;
    float* psum  = w;
    float* pmax  = psum  + (size_t)NS * BEc;
    float* pmin  = pmax  + (size_t)NS * BEc;
    float* psumB = pmin  + (size_t)NS * BEc;
    float* pmaxB = psumB + (size_t)NP * BEc;
    float* pminB = pmaxB + (size_t)NP * BEc;
    float* cbuf  = pminB + (size_t)NP * BEc;
    float* embuf = cbuf  + BEc;
    float* rdbuf = embuf + BEc;
    float* pden  = psum;    // reused after K2a
    float* pdenB = psumB;   // reused after K2b

    dim3 gridP(NS, Bc);
    dim3 gridR(NP, BEc / 256);
    sa_stats_part<SCmain><<<gridP, 256, 0, stream>>>(q, k, psum, pmax, pmin);
    sa_red3<<<gridR, 256, 0, stream>>>(psum, pmax, pmin, psumB, pmaxB, pminB, SC2);
    sa_stats_fin<<<BEc / 256, 256, 0, stream>>>(psumB, pmaxB, pminB, cbuf, embuf);
    sa_den_part<SCmain><<<gridP, 256, 0, stream>>>(q, cbuf, embuf, pden);
    sa_red1<<<gridR, 256, 0, stream>>>(pden, pdenB, SC2);
    sa_den_fin<<<BEc / 256, 256, 0, stream>>>(pdenB, rdbuf);
    sa_out<SCmain><<<gridP, 256, 0, stream>>>(q, v, cbuf, embuf, rdbuf, out);
}